// Round 2
// baseline (837.682 us; speedup 1.0000x reference)
//
#include <hip/hip_runtime.h>
#include <hip/hip_bf16.h>
#include <math.h>

#define HDIM 4096
#define NEXP 256
#define BM   32
#define BK   32
#define TOPK 8
#define NGRP 8
#define DROPG 4

#define XS_PAD 36    // BM+4: rows stay 16B-aligned, odd-ish bank spread
#define WS_PAD 260   // NEXP+4

// ---------------- Kernel A: scores = sigmoid(x @ W^T) ----------------
// grid: ntok/BM blocks of 256 threads. Thread (tm,tn)=(tid>>5, tid&31)
// computes a 4-token x 8-expert micro-tile.
__global__ __launch_bounds__(256, 2)
void gate_gemm_sigmoid(const float* __restrict__ x,
                       const float* __restrict__ w,
                       float* __restrict__ scores)
{
    __shared__ float xs[BK][XS_PAD];    // transposed: xs[k][token]
    __shared__ float wsh[BK][WS_PAD];   // transposed: wsh[k][expert]

    const int tid = threadIdx.x;
    const int tm = tid >> 5;    // 0..7   -> tokens tm*4 .. tm*4+3
    const int tn = tid & 31;    // 0..31  -> experts tn*8 .. tn*8+7
    const long m0 = (long)blockIdx.x * BM;

    float acc[4][8];
#pragma unroll
    for (int i = 0; i < 4; ++i)
#pragma unroll
        for (int j = 0; j < 8; ++j) acc[i][j] = 0.f;

    const int xt = tid >> 3;         // token slot 0..31
    const int xk = (tid & 7) * 4;    // k offset 0,4,..,28

    for (int k0 = 0; k0 < HDIM; k0 += BK) {
        // issue global loads before the barrier (overlap with prev compute)
        float4 xv = *reinterpret_cast<const float4*>(
            &x[(m0 + xt) * HDIM + k0 + xk]);
        float4 wv[8];
#pragma unroll
        for (int i = 0; i < 8; ++i) {
            int e = i * 32 + (tid >> 3);
            wv[i] = *reinterpret_cast<const float4*>(
                &w[(long)e * HDIM + k0 + xk]);
        }
        __syncthreads();   // previous iteration's readers done
        xs[xk + 0][xt] = xv.x;
        xs[xk + 1][xt] = xv.y;
        xs[xk + 2][xt] = xv.z;
        xs[xk + 3][xt] = xv.w;
#pragma unroll
        for (int i = 0; i < 8; ++i) {
            int e = i * 32 + (tid >> 3);
            wsh[xk + 0][e] = wv[i].x;
            wsh[xk + 1][e] = wv[i].y;
            wsh[xk + 2][e] = wv[i].z;
            wsh[xk + 3][e] = wv[i].w;
        }
        __syncthreads();
#pragma unroll
        for (int kk = 0; kk < BK; ++kk) {
            float4 xf = *reinterpret_cast<const float4*>(&xs[kk][tm * 4]);
            float4 w0 = *reinterpret_cast<const float4*>(&wsh[kk][tn * 8]);
            float4 w1 = *reinterpret_cast<const float4*>(&wsh[kk][tn * 8 + 4]);
            float xr[4] = {xf.x, xf.y, xf.z, xf.w};
            float wr[8] = {w0.x, w0.y, w0.z, w0.w, w1.x, w1.y, w1.z, w1.w};
#pragma unroll
            for (int i = 0; i < 4; ++i)
#pragma unroll
                for (int j = 0; j < 8; ++j)
                    acc[i][j] = fmaf(xr[i], wr[j], acc[i][j]);
        }
    }

    // epilogue: sigmoid + coalesced float4 stores
#pragma unroll
    for (int i = 0; i < 4; ++i) {
        long t = m0 + tm * 4 + i;
        float4 o0, o1;
        o0.x = 1.f / (1.f + expf(-acc[i][0]));
        o0.y = 1.f / (1.f + expf(-acc[i][1]));
        o0.z = 1.f / (1.f + expf(-acc[i][2]));
        o0.w = 1.f / (1.f + expf(-acc[i][3]));
        o1.x = 1.f / (1.f + expf(-acc[i][4]));
        o1.y = 1.f / (1.f + expf(-acc[i][5]));
        o1.z = 1.f / (1.f + expf(-acc[i][6]));
        o1.w = 1.f / (1.f + expf(-acc[i][7]));
        float* dst = &scores[t * NEXP + tn * 8];
        *reinterpret_cast<float4*>(dst)     = o0;
        *reinterpret_cast<float4*>(dst + 4) = o1;
    }
}

// ---------------- Kernel B: grouped top-k gating, 1 wave per token ----------
// NOTE: indices are written as FLOAT VALUES — the harness's d_out is the
// concatenation of (int32 inds, f32 sel) promoted to float32 (JAX concat
// promotion), so 37 must be stored as 37.0f.
__global__ __launch_bounds__(64, 8)
void gate_topk(const float* __restrict__ scores,
               const float* __restrict__ bias,
               float* __restrict__ out_idx,
               float* __restrict__ out_val)
{
    __shared__ float so[NEXP];   // orig sigmoid scores
    __shared__ float sb[NEXP];   // biased scores (for group top-2)
    __shared__ float gsc[NGRP];

    const long t = blockIdx.x;
    const int l = threadIdx.x;

    float bv[4];
    int ce[4];
#pragma unroll
    for (int j = 0; j < 4; ++j) {
        int e = l + 64 * j;
        float s = scores[t * NEXP + e];
        float b = s + bias[e];
        so[e] = s;
        sb[e] = b;
        bv[j] = b;
        ce[j] = e;
    }
    __syncthreads();

    // group score = sum of top-2 biased scores within the group
    if (l < NGRP) {
        float m1 = -1e30f, m2 = -1e30f;
        int base = l * 32;
        for (int i = 0; i < 32; ++i) {
            float v = sb[base + i];
            if (v > m1) { m2 = m1; m1 = v; }
            else if (v > m2) { m2 = v; }
        }
        gsc[l] = m1 + m2;
    }
    __syncthreads();

    // drop the 4 lowest-scoring groups (ties: lowest index dropped first,
    // matching top_k(-g, 4) semantics)
    float g[8];
#pragma unroll
    for (int i = 0; i < 8; ++i) g[i] = gsc[i];
    unsigned dropped = 0;
    for (int it = 0; it < DROPG; ++it) {
        float mn = 1e38f; int mi = 0;
#pragma unroll
        for (int i = 0; i < 8; ++i) {
            bool alive = !((dropped >> i) & 1);
            if (alive && g[i] < mn) { mn = g[i]; mi = i; }
        }
        dropped |= 1u << mi;
    }

    // candidates: dropped groups -> exactly 0.0f (matches reference mask)
    float cv[4];
#pragma unroll
    for (int j = 0; j < 4; ++j) {
        int grp = ce[j] >> 5;
        cv[j] = ((dropped >> grp) & 1) ? 0.0f : bv[j];
    }

    // top-8 via 8 rounds of wave-wide argmax
    // (lexicographic: larger value wins; equal value -> smaller index wins)
    int ind[8];
#pragma unroll
    for (int r = 0; r < TOPK; ++r) {
        float lv = -1e38f; int li = 0x7fffffff;
#pragma unroll
        for (int j = 0; j < 4; ++j) {
            if (cv[j] > lv || (cv[j] == lv && ce[j] < li)) { lv = cv[j]; li = ce[j]; }
        }
#pragma unroll
        for (int off = 32; off >= 1; off >>= 1) {
            float ov = __shfl_xor(lv, off);
            int   oi = __shfl_xor(li, off);
            if (ov > lv || (ov == lv && oi < li)) { lv = ov; li = oi; }
        }
        ind[r] = li;
#pragma unroll
        for (int j = 0; j < 4; ++j)
            if (ce[j] == li) cv[j] = -1e38f;   // remove winner
    }

    // gather orig scores of winners, normalize, scale
    int myi = 0;
#pragma unroll
    for (int r = 0; r < TOPK; ++r)
        if (l == r) myi = ind[r];
    float sv = (l < TOPK) ? so[myi] : 0.f;
    float sum = sv;
#pragma unroll
    for (int off = 1; off < TOPK; off <<= 1)
        sum += __shfl_xor(sum, off);
    if (l < TOPK) {
        out_idx[t * TOPK + l] = (float)myi;               // index as float value
        out_val[t * TOPK + l] = sv / (sum + 1e-20f) * 2.5f;
    }
}

extern "C" void kernel_launch(void* const* d_in, const int* in_sizes, int n_in,
                              void* d_out, int out_size, void* d_ws, size_t ws_size,
                              hipStream_t stream) {
    const float* x    = (const float*)d_in[0];   // [B*S, H]
    const float* w    = (const float*)d_in[1];   // [E, H]
    const float* bias = (const float*)d_in[2];   // [E]

    const int ntok = in_sizes[0] / HDIM;         // 16384

    float* scores = (float*)d_ws;                // [ntok, NEXP] = 16 MiB
    float* out_i  = (float*)d_out;               // [ntok, 8] indices (as floats)
    float* out_v  = (float*)d_out + (long)ntok * TOPK;  // [ntok, 8] weights

    gate_gemm_sigmoid<<<ntok / BM, 256, 0, stream>>>(x, w, scores);
    gate_topk<<<ntok, 64, 0, stream>>>(scores, bias, out_i, out_v);
}

// Round 3
// 782.266 us; speedup vs baseline: 1.0708x; 1.0708x over previous
//
#include <hip/hip_runtime.h>
#include <hip/hip_bf16.h>
#include <math.h>
#include <stdint.h>

#define HDIM   4096
#define NEXP   256
#define TOPK   8
#define NGRP   8
#define NTOK   16384
#define KSPLIT 2
#define BM     64
#define BK     32
#define KCHUNKS (HDIM/BK)      /* 128 */
#define NIT    ((HDIM/KSPLIT)/BK)  /* 64 */
#define TAU    2.5e-5f         /* expert-gap flag threshold (~20 sigma of split error) */
#define TAUG   5.0e-5f         /* group-margin flag threshold */

typedef __attribute__((ext_vector_type(8))) short short8v;  /* 8 bf16 = 4 VGPR */
typedef __attribute__((ext_vector_type(4))) float f32x4;

/* ---- ws layout (bytes) ----
   partials[2][NTOK][256] f32 : 33,554,432
   W split bf16 hi/lo         :  4,194,304  ([kc][plane][kb][col 256][8 bf16])
   flag counter (4B) + list   */
#define WS_WSPLIT  (2ull*NTOK*NEXP*4)
#define WS_CTR     (WS_WSPLIT + 4ull*1024*1024)
#define WS_LIST    (WS_CTR + 256)

__device__ inline void gload_lds16(const void* g, void* l) {
    __builtin_amdgcn_global_load_lds(
        (const __attribute__((address_space(1))) unsigned int*)g,
        (__attribute__((address_space(3))) unsigned int*)l, 16, 0, 0);
}

__device__ inline unsigned rtn16(unsigned u) {  /* round-to-nearest bf16 of f32 bits */
    return (u + 0x7fffu + ((u >> 16) & 1u)) >> 16;
}

/* ================= Kernel 1: split W into bf16 hi/lo, GEMM-ready layout ========= */
__global__ __launch_bounds__(256)
void convert_w(const float* __restrict__ w, unsigned short* __restrict__ wws)
{
    int gid  = blockIdx.x * 256 + threadIdx.x;   /* 131072 = 256 experts * 512 cells */
    int e    = gid >> 9;
    int cell = gid & 511;                        /* k0 = cell*8 */
    int kc = cell >> 2, kb = cell & 3;
    const float* src = w + (size_t)e * HDIM + cell * 8;
    float4 f0 = *(const float4*)src;
    float4 f1 = *(const float4*)(src + 4);
    float fs[8] = {f0.x,f0.y,f0.z,f0.w,f1.x,f1.y,f1.z,f1.w};
    unsigned hw[4], lw[4];
#pragma unroll
    for (int p = 0; p < 4; ++p) {
        unsigned u0 = __float_as_uint(fs[2*p]);
        unsigned u1 = __float_as_uint(fs[2*p+1]);
        unsigned h0 = rtn16(u0), h1 = rtn16(u1);
        float r0 = fs[2*p]   - __uint_as_float(h0 << 16);
        float r1 = fs[2*p+1] - __uint_as_float(h1 << 16);
        unsigned l0 = rtn16(__float_as_uint(r0));
        unsigned l1 = rtn16(__float_as_uint(r1));
        hw[p] = h0 | (h1 << 16);
        lw[p] = l0 | (l1 << 16);
    }
    /* ushort index: ((kc*2 + plane)*4 + kb)*2048 + e*8 */
    size_t bh = ((size_t)(kc*2 + 0)*4 + kb)*2048 + e*8;
    size_t blo= ((size_t)(kc*2 + 1)*4 + kb)*2048 + e*8;
    *(uint4*)&wws[bh]  = make_uint4(hw[0],hw[1],hw[2],hw[3]);
    *(uint4*)&wws[blo] = make_uint4(lw[0],lw[1],lw[2],lw[3]);
}

/* ================= Kernel 2: split-K MFMA GEMM (hi/lo bf16) ===================== */
/* grid 512: mb = bx&255 (64-token tile), ks = bx>>8 (K half). 4 waves, wave=64x64. */
__global__ __launch_bounds__(256, 2)
void gate_gemm(const float* __restrict__ x, const unsigned short* __restrict__ wws,
               float* __restrict__ partials)
{
    __shared__ uint4 ldsv[2560];            /* 40 KiB: A 8K ([pl][kb][64][16B]) + B 32K */
    char* lds = (char*)ldsv;
    const int t = threadIdx.x;
    const int wid = t >> 6, lane = t & 63;
    const int mb = blockIdx.x & 255, ks = blockIdx.x >> 8;
    const size_t m0 = (size_t)mb * BM;
    const int frow = lane & 15, fkb = lane >> 4;
    const int srow = t & 63, skb = t >> 6;  /* staging: row, kb-cell */

    f32x4 acc[4][4];
#pragma unroll
    for (int m = 0; m < 4; ++m)
#pragma unroll
        for (int n = 0; n < 4; ++n) acc[m][n] = (f32x4){0.f,0.f,0.f,0.f};

    const float* xrow = x + (m0 + srow) * HDIM + ks * (HDIM/KSPLIT) + skb * 8;
    const char* wbase = (const char*)wws + (size_t)(ks * (KCHUNKS/KSPLIT)) * 32768;

    float4 xa = *(const float4*)(xrow);
    float4 xb = *(const float4*)(xrow + 4);

    for (int it = 0; it < NIT; ++it) {
        __syncthreads();                     /* LDS free (prev compute done) */
        /* ---- A stage: trunc-hi + RTN-lo split, conflict-free layout ---- */
        {
            float fs[8] = {xa.x,xa.y,xa.z,xa.w,xb.x,xb.y,xb.z,xb.w};
            unsigned hw[4], lw[4];
#pragma unroll
            for (int p = 0; p < 4; ++p) {
                unsigned u0 = __float_as_uint(fs[2*p]);
                unsigned u1 = __float_as_uint(fs[2*p+1]);
                hw[p] = (u0 >> 16) | (u1 & 0xffff0000u);
                float r0 = fs[2*p]   - __uint_as_float(u0 & 0xffff0000u);
                float r1 = fs[2*p+1] - __uint_as_float(u1 & 0xffff0000u);
                unsigned l0 = rtn16(__float_as_uint(r0));
                unsigned l1 = rtn16(__float_as_uint(r1));
                lw[p] = l0 | (l1 << 16);
            }
            *(uint4*)&lds[skb*1024 + srow*16]        = make_uint4(hw[0],hw[1],hw[2],hw[3]);
            *(uint4*)&lds[4096 + skb*1024 + srow*16] = make_uint4(lw[0],lw[1],lw[2],lw[3]);
        }
        /* ---- B stage: linear global_load_lds from pre-arranged W ---- */
        {
            const char* wsrc = wbase + (size_t)it * 32768;
#pragma unroll
            for (int j = 0; j < 8; ++j) {
                int chunk = wid * 8 + j;
                gload_lds16(wsrc + chunk*1024 + lane*16, &lds[8192 + chunk*1024]);
            }
        }
        __syncthreads();                     /* vmcnt(0): B landed, A visible */
        if (it + 1 < NIT) {                  /* A prefetch: drains at NEXT top barrier */
            xa = *(const float4*)(xrow + (it+1)*BK);
            xb = *(const float4*)(xrow + (it+1)*BK + 4);
        }
        /* ---- compute: 48 MFMAs (hh, hl, lh) ---- */
        short8v ah[4], al[4];
#pragma unroll
        for (int m = 0; m < 4; ++m) {
            ah[m] = *(const short8v*)&lds[        fkb*1024 + (m*16+frow)*16];
            al[m] = *(const short8v*)&lds[4096 +  fkb*1024 + (m*16+frow)*16];
        }
#pragma unroll
        for (int n = 0; n < 4; ++n) {
            int col = wid*64 + n*16 + frow;
            short8v bh = *(const short8v*)&lds[8192 +         fkb*4096 + col*16];
            short8v bl = *(const short8v*)&lds[8192 + 16384 + fkb*4096 + col*16];
#pragma unroll
            for (int m = 0; m < 4; ++m)
                acc[m][n] = __builtin_amdgcn_mfma_f32_16x16x32_bf16(ah[m], bh, acc[m][n], 0,0,0);
#pragma unroll
            for (int m = 0; m < 4; ++m)
                acc[m][n] = __builtin_amdgcn_mfma_f32_16x16x32_bf16(ah[m], bl, acc[m][n], 0,0,0);
#pragma unroll
            for (int m = 0; m < 4; ++m)
                acc[m][n] = __builtin_amdgcn_mfma_f32_16x16x32_bf16(al[m], bh, acc[m][n], 0,0,0);
        }
    }
    /* epilogue: C/D layout col=lane&15, row=(lane>>4)*4+r (m89-verified) */
    float* pb = partials + (size_t)ks * NTOK * NEXP;
#pragma unroll
    for (int m = 0; m < 4; ++m)
#pragma unroll
        for (int n = 0; n < 4; ++n) {
            int col = wid*64 + n*16 + (lane & 15);
#pragma unroll
            for (int r = 0; r < 4; ++r) {
                size_t row = m0 + m*16 + (lane >> 4)*4 + r;
                pb[row*NEXP + col] = acc[m][n][r];
            }
        }
}

/* ================= wave-level gating (shared by topk + refine) ================== */
__device__ void wave_gate_topk(float* gb /*[256] gates in -> biased*/, float* ss /*[256]*/,
                               const float* __restrict__ bias, int lane, size_t tok,
                               float* __restrict__ oIdx, float* __restrict__ oVal,
                               unsigned* flagCtr, int* flagList)
{
    float bv[4]; int ce[4];
#pragma unroll
    for (int j = 0; j < 4; ++j) {
        int e = lane + 64*j;
        float s = 1.f / (1.f + expf(-gb[e]));
        float b = s + bias[e];
        ss[e] = s; gb[e] = b;
        bv[j] = b; ce[j] = e;
    }
    /* group top-2 sums: 8 lanes per group, merge via shfl_xor */
    int g = lane >> 3;
    float4 gv = *(const float4*)(gb + g*32 + (lane & 7)*4);
    float a1 = fmaxf(gv.x,gv.y), a2 = fminf(gv.x,gv.y);
    float b1 = fmaxf(gv.z,gv.w), b2 = fminf(gv.z,gv.w);
    float m1 = fmaxf(a1,b1);
    float m2 = fmaxf(fminf(a1,b1), fmaxf(a2,b2));
#pragma unroll
    for (int off = 1; off < 8; off <<= 1) {
        float om1 = __shfl_xor(m1, off), om2 = __shfl_xor(m2, off);
        float n1 = fmaxf(m1, om1);
        float n2 = fmaxf(fminf(m1, om1), fmaxf(m2, om2));
        m1 = n1; m2 = n2;
    }
    float gs = m1 + m2;
    float gsc[8];
#pragma unroll
    for (int i = 0; i < 8; ++i) gsc[i] = __shfl(gs, i*8);
    /* drop 4 lowest groups (stable: first index at strict min) */
    unsigned dropped = 0; float lastdrop = 0.f;
#pragma unroll
    for (int itd = 0; itd < 4; ++itd) {
        float mn = 1e38f; int mi = 0;
#pragma unroll
        for (int i = 0; i < 8; ++i)
            if (!((dropped >> i) & 1) && gsc[i] < mn) { mn = gsc[i]; mi = i; }
        dropped |= 1u << mi; lastdrop = mn;
    }
    float minkeep = 1e38f;
#pragma unroll
    for (int i = 0; i < 8; ++i)
        if (!((dropped >> i) & 1)) minkeep = fminf(minkeep, gsc[i]);
    float gmargin = minkeep - lastdrop;

    float cv[4];
#pragma unroll
    for (int j = 0; j < 4; ++j)
        cv[j] = ((dropped >> (ce[j] >> 5)) & 1) ? 0.0f : bv[j];

    /* 9 wave-argmax rounds (value desc, index asc) -> top-8 + boundary value */
    float vals[9]; int ind[9];
#pragma unroll
    for (int r = 0; r < 9; ++r) {
        float lv = -1e38f; int li = 0x7fffffff;
#pragma unroll
        for (int j = 0; j < 4; ++j)
            if (cv[j] > lv || (cv[j] == lv && ce[j] < li)) { lv = cv[j]; li = ce[j]; }
#pragma unroll
        for (int off = 32; off >= 1; off >>= 1) {
            float ov = __shfl_xor(lv, off);
            int   oi = __shfl_xor(li, off);
            if (ov > lv || (ov == lv && oi < li)) { lv = ov; li = oi; }
        }
        vals[r] = lv; ind[r] = li;
#pragma unroll
        for (int j = 0; j < 4; ++j)
            if (ce[j] == li) cv[j] = -1e38f;
    }
    float mingap = 1e38f;
#pragma unroll
    for (int r = 0; r < 8; ++r) mingap = fminf(mingap, vals[r] - vals[r+1]);

    int myi = 0;
#pragma unroll
    for (int r = 0; r < 8; ++r) if (lane == r) myi = ind[r];
    float sv = (lane < 8) ? ss[myi] : 0.f;
    float sum = sv;
#pragma unroll
    for (int off = 1; off < 8; off <<= 1) sum += __shfl_xor(sum, off);
    if (lane < 8) {
        oIdx[tok*8 + lane] = (float)myi;
        oVal[tok*8 + lane] = sv / (sum + 1e-20f) * 2.5f;
    }
    if (flagCtr && lane == 0 && (mingap < TAU || gmargin < TAUG)) {
        unsigned p = atomicAdd(flagCtr, 1u);
        flagList[p] = (int)tok;
    }
}

/* ================= Kernel 3: reduce partials + sigmoid + gating (4 tok/block) === */
__global__ __launch_bounds__(256, 4)
void gate_topk(const float* __restrict__ partials, const float* __restrict__ bias,
               float* __restrict__ oIdx, float* __restrict__ oVal,
               unsigned* ctr, int* list)
{
    __shared__ float gb[4][256];
    __shared__ float ss[4][256];
    int wid = threadIdx.x >> 6, lane = threadIdx.x & 63;
    size_t tok = (size_t)blockIdx.x * 4 + wid;
    const float* p0 = partials + tok * NEXP;
    const float* p1 = partials + (size_t)NTOK * NEXP + tok * NEXP;
#pragma unroll
    for (int j = 0; j < 4; ++j) {
        int e = lane + 64*j;
        gb[wid][e] = p0[e] + p1[e];
    }
    wave_gate_topk(gb[wid], ss[wid], bias, lane, tok, oIdx, oVal, ctr, list);
}

/* ================= Kernel 4: fp32 recompute of margin-flagged tokens ============ */
__global__ __launch_bounds__(256, 2)
void gate_refine(const float* __restrict__ x, const float* __restrict__ w,
                 const float* __restrict__ bias,
                 float* __restrict__ oIdx, float* __restrict__ oVal,
                 const unsigned* __restrict__ ctr, const int* __restrict__ list)
{
    __shared__ float gb[4][256];
    __shared__ float ss[4][256];
    int nf = (int)*ctr;
    int nb = (nf + 3) >> 2;
    int e = threadIdx.x;
    int wid = threadIdx.x >> 6, lane = threadIdx.x & 63;
    for (int batch = blockIdx.x; batch < nb; batch += gridDim.x) {
        int tcount = nf - batch*4; if (tcount > 4) tcount = 4;
        int tk[4];
#pragma unroll
        for (int i = 0; i < 4; ++i) {
            int ii = i < tcount ? i : tcount - 1;
            tk[i] = list[batch*4 + ii];
        }
        const float* wr = w + (size_t)e * HDIM;
        const float* x0 = x + (size_t)tk[0] * HDIM;
        const float* x1 = x + (size_t)tk[1] * HDIM;
        const float* x2 = x + (size_t)tk[2] * HDIM;
        const float* x3 = x + (size_t)tk[3] * HDIM;
        float a0=0.f, a1=0.f, a2=0.f, a3=0.f;
        for (int k = 0; k < HDIM; k += 4) {
            float4 wv = *(const float4*)(wr + k);
            float4 v0 = *(const float4*)(x0 + k);   /* uniform -> scalar loads */
            float4 v1 = *(const float4*)(x1 + k);
            float4 v2 = *(const float4*)(x2 + k);
            float4 v3 = *(const float4*)(x3 + k);
            a0 += wv.x*v0.x + wv.y*v0.y + wv.z*v0.z + wv.w*v0.w;
            a1 += wv.x*v1.x + wv.y*v1.y + wv.z*v1.z + wv.w*v1.w;
            a2 += wv.x*v2.x + wv.y*v2.y + wv.z*v2.z + wv.w*v2.w;
            a3 += wv.x*v3.x + wv.y*v3.y + wv.z*v3.z + wv.w*v3.w;
        }
        __syncthreads();            /* previous batch's readers done */
        gb[0][e] = a0; gb[1][e] = a1; gb[2][e] = a2; gb[3][e] = a3;
        __syncthreads();
        if (wid < tcount)
            wave_gate_topk(gb[wid], ss[wid], bias, lane, (size_t)tk[wid],
                           oIdx, oVal, nullptr, nullptr);
    }
}

extern "C" void kernel_launch(void* const* d_in, const int* in_sizes, int n_in,
                              void* d_out, int out_size, void* d_ws, size_t ws_size,
                              hipStream_t stream) {
    const float* x    = (const float*)d_in[0];
    const float* w    = (const float*)d_in[1];
    const float* bias = (const float*)d_in[2];
    const int ntok = in_sizes[0] / HDIM;          /* 16384 */

    char* ws = (char*)d_ws;
    float* partials      = (float*)ws;
    unsigned short* wws  = (unsigned short*)(ws + WS_WSPLIT);
    unsigned* ctr        = (unsigned*)(ws + WS_CTR);
    int* list            = (int*)(ws + WS_LIST);
    float* oIdx = (float*)d_out;
    float* oVal = (float*)d_out + (size_t)ntok * TOPK;

    hipMemsetAsync(ctr, 0, 4, stream);
    convert_w <<<512, 256, 0, stream>>>(w, wws);
    gate_gemm <<<(ntok/BM) * KSPLIT, 256, 0, stream>>>(x, wws, partials);
    gate_topk <<<ntok/4, 256, 0, stream>>>(partials, bias, oIdx, oVal, ctr, list);
    gate_refine<<<256, 256, 0, stream>>>(x, w, bias, oIdx, oVal, ctr, list);
}

// Round 4
// 704.689 us; speedup vs baseline: 1.1887x; 1.1101x over previous
//
#include <hip/hip_runtime.h>
#include <hip/hip_bf16.h>
#include <math.h>
#include <stdint.h>

#define HDIM   4096
#define NEXP   256
#define TOPK   8
#define NGRP   8
#define NTOK   16384
#define KSPLIT 2
#define BM     64
#define BK     32
#define KCHUNKS (HDIM/BK)          /* 128 */
#define NIT    ((HDIM/KSPLIT)/BK)  /* 64 */
#define TAU    2.5e-5f             /* expert-gap flag threshold */
#define TAUG   5.0e-5f             /* group-margin flag threshold */

typedef __attribute__((ext_vector_type(8))) short short8v;  /* 8 bf16 = 4 VGPR */
typedef __attribute__((ext_vector_type(4))) float f32x4;

/* ---- ws layout (bytes) ----
   partials[2][NTOK][256] f32 : 33,554,432
   W split bf16 hi/lo         :  4,194,304
   flag counter + list        */
#define WS_WSPLIT  (2ull*NTOK*NEXP*4)
#define WS_CTR     (WS_WSPLIT + 4ull*1024*1024)
#define WS_LIST    (WS_CTR + 256)

__device__ inline void gload_lds16(const void* g, void* l) {
    __builtin_amdgcn_global_load_lds(
        (const __attribute__((address_space(1))) unsigned int*)g,
        (__attribute__((address_space(3))) unsigned int*)l, 16, 0, 0);
}

__device__ inline unsigned rtn16(unsigned u) {  /* round-to-nearest bf16 of f32 bits */
    return (u + 0x7fffu + ((u >> 16) & 1u)) >> 16;
}

/* ================= Kernel 1: split W into bf16 hi/lo, GEMM-ready layout =========
   Layout (ushorts): chunk = ((kc*2 + plane)*16 + c) of 512 ushorts (1 KiB);
   within chunk, lane = (e&15)*4 + kb holds w[e][kc*32 + kb*8 .. +8).
   This makes the GEMM's B-stage a linear lane-ordered global_load_lds AND the
   B ds_read_b128 layout [col][kb][16B] (64B rows -> 2-way banks = free).     */
__global__ __launch_bounds__(256)
void convert_w(const float* __restrict__ w, unsigned short* __restrict__ wws)
{
    int gid  = blockIdx.x * 256 + threadIdx.x;   /* 131072 = 256 experts * 512 cells */
    int e    = gid >> 9;
    int cell = gid & 511;                        /* k0 = cell*8 */
    int kc = cell >> 2, kb = cell & 3;
    const float* src = w + (size_t)e * HDIM + cell * 8;
    float4 f0 = *(const float4*)src;
    float4 f1 = *(const float4*)(src + 4);
    float fs[8] = {f0.x,f0.y,f0.z,f0.w,f1.x,f1.y,f1.z,f1.w};
    unsigned hw[4], lw[4];
#pragma unroll
    for (int p = 0; p < 4; ++p) {
        unsigned u0 = __float_as_uint(fs[2*p]);
        unsigned u1 = __float_as_uint(fs[2*p+1]);
        unsigned h0 = rtn16(u0), h1 = rtn16(u1);
        float r0 = fs[2*p]   - __uint_as_float(h0 << 16);
        float r1 = fs[2*p+1] - __uint_as_float(h1 << 16);
        unsigned l0 = rtn16(__float_as_uint(r0));
        unsigned l1 = rtn16(__float_as_uint(r1));
        hw[p] = h0 | (h1 << 16);
        lw[p] = l0 | (l1 << 16);
    }
    int lane = (e & 15) * 4 + kb;
    int c    = e >> 4;
    size_t bh = ((size_t)(kc*2 + 0)*16 + c)*512 + lane*8;
    size_t bl = ((size_t)(kc*2 + 1)*16 + c)*512 + lane*8;
    *(uint4*)&wws[bh] = make_uint4(hw[0],hw[1],hw[2],hw[3]);
    *(uint4*)&wws[bl] = make_uint4(lw[0],lw[1],lw[2],lw[3]);
}

/* ================= Kernel 2: split-K MFMA GEMM (hi/lo bf16) =====================
   512 blocks x 512 threads (8 waves). mb = bx&255 (64-token tile), ks = bx>>8.
   Wave tile 64x32 (m=4, n=2), 24 MFMAs/iter/wave. 2 blocks/CU = 16 waves/CU.
   LDS 40KB: A [plane2][row64][kb4][16B] (8K) + B [plane2][chunk16][lane64*16B] (32K).
   Both A and B ds_read_b128 hit 64B-interleaved rows -> 2-way banks (free).   */
__global__ __launch_bounds__(512, 4)
void gate_gemm(const float* __restrict__ x, const unsigned short* __restrict__ wws,
               float* __restrict__ partials)
{
    __shared__ uint4 ldsv[2560];            /* 40 KiB */
    char* lds = (char*)ldsv;
    const int t = threadIdx.x;
    const int wid = t >> 6, lane = t & 63;
    const int mb = blockIdx.x & 255, ks = blockIdx.x >> 8;
    const size_t m0 = (size_t)mb * BM;
    const int frow = lane & 15, fkb = lane >> 4;

    f32x4 acc[4][2];
#pragma unroll
    for (int m = 0; m < 4; ++m)
#pragma unroll
        for (int n = 0; n < 2; ++n) acc[m][n] = (f32x4){0.f,0.f,0.f,0.f};

    /* A staging: threads 0..255, thread t -> row t>>2, kb t&3 */
    const int srow = t >> 2, skb = t & 3;
    const float* xrow = x + (m0 + srow) * HDIM + ks * (HDIM/KSPLIT) + skb * 8;
    const char* wbase = (const char*)wws + (size_t)ks * (KCHUNKS/KSPLIT) * 32768;

    float4 xa, xb;
    if (t < 256) { xa = *(const float4*)(xrow); xb = *(const float4*)(xrow + 4); }

    for (int it = 0; it < NIT; ++it) {
        __syncthreads();                     /* LDS free (prev compute done) */
        if (t < 256) {                       /* A stage: RTN hi + RTN lo */
            float fs[8] = {xa.x,xa.y,xa.z,xa.w,xb.x,xb.y,xb.z,xb.w};
            unsigned hw[4], lw[4];
#pragma unroll
            for (int p = 0; p < 4; ++p) {
                unsigned u0 = __float_as_uint(fs[2*p]);
                unsigned u1 = __float_as_uint(fs[2*p+1]);
                unsigned h0 = rtn16(u0), h1 = rtn16(u1);
                float r0 = fs[2*p]   - __uint_as_float(h0 << 16);
                float r1 = fs[2*p+1] - __uint_as_float(h1 << 16);
                lw[p] = rtn16(__float_as_uint(r0)) | (rtn16(__float_as_uint(r1)) << 16);
                hw[p] = h0 | (h1 << 16);
            }
            *(uint4*)&lds[       t*16] = make_uint4(hw[0],hw[1],hw[2],hw[3]);
            *(uint4*)&lds[4096 + t*16] = make_uint4(lw[0],lw[1],lw[2],lw[3]);
        }
        {   /* B stage: 32 chunks (2 planes x 16), 4 per wave, linear LDS */
            const char* wsrc = wbase + (size_t)it * 32768;
#pragma unroll
            for (int j = 0; j < 4; ++j) {
                int idx = wid * 4 + j;       /* = plane*16 + chunk */
                gload_lds16(wsrc + idx*1024 + lane*16, &lds[8192 + idx*1024]);
            }
        }
        __syncthreads();                     /* vmcnt(0): B landed, A visible */
        if (t < 256 && it + 1 < NIT) {       /* A prefetch overlaps compute */
            xa = *(const float4*)(xrow + (it+1)*BK);
            xb = *(const float4*)(xrow + (it+1)*BK + 4);
        }
        /* compute: 24 MFMAs (hh, hl, lh) */
        short8v ah[4], al[4];
#pragma unroll
        for (int m = 0; m < 4; ++m) {
            int ao = (m*16 + frow)*64 + fkb*16;
            ah[m] = *(const short8v*)&lds[ao];
            al[m] = *(const short8v*)&lds[4096 + ao];
        }
#pragma unroll
        for (int n = 0; n < 2; ++n) {
            int bo = 8192 + (wid*2 + n)*1024 + (frow*4 + fkb)*16;
            short8v bh = *(const short8v*)&lds[bo];
            short8v bl = *(const short8v*)&lds[bo + 16384];
#pragma unroll
            for (int m = 0; m < 4; ++m)
                acc[m][n] = __builtin_amdgcn_mfma_f32_16x16x32_bf16(ah[m], bh, acc[m][n], 0,0,0);
#pragma unroll
            for (int m = 0; m < 4; ++m)
                acc[m][n] = __builtin_amdgcn_mfma_f32_16x16x32_bf16(ah[m], bl, acc[m][n], 0,0,0);
#pragma unroll
            for (int m = 0; m < 4; ++m)
                acc[m][n] = __builtin_amdgcn_mfma_f32_16x16x32_bf16(al[m], bh, acc[m][n], 0,0,0);
        }
    }
    /* epilogue: C/D layout col=lane&15, row=(lane>>4)*4+r (m89-verified) */
    float* pb = partials + (size_t)ks * NTOK * NEXP;
#pragma unroll
    for (int m = 0; m < 4; ++m)
#pragma unroll
        for (int n = 0; n < 2; ++n) {
            int col = wid*32 + n*16 + (lane & 15);
#pragma unroll
            for (int r = 0; r < 4; ++r) {
                size_t row = m0 + m*16 + (lane >> 4)*4 + r;
                pb[row*NEXP + col] = acc[m][n][r];
            }
        }
}

/* ================= wave-level gating (shared by topk + refine) ================== */
__device__ void wave_gate_topk(float* gb /*[256] gates in -> biased*/, float* ss /*[256]*/,
                               const float* __restrict__ bias, int lane, size_t tok,
                               float* __restrict__ oIdx, float* __restrict__ oVal,
                               unsigned* flagCtr, int* flagList)
{
    float bv[4]; int ce[4];
#pragma unroll
    for (int j = 0; j < 4; ++j) {
        int e = lane + 64*j;
        float s = 1.f / (1.f + expf(-gb[e]));
        float b = s + bias[e];
        ss[e] = s; gb[e] = b;
        bv[j] = b; ce[j] = e;
    }
    int g = lane >> 3;
    float4 gv = *(const float4*)(gb + g*32 + (lane & 7)*4);
    float a1 = fmaxf(gv.x,gv.y), a2 = fminf(gv.x,gv.y);
    float b1 = fmaxf(gv.z,gv.w), b2 = fminf(gv.z,gv.w);
    float m1 = fmaxf(a1,b1);
    float m2 = fmaxf(fminf(a1,b1), fmaxf(a2,b2));
#pragma unroll
    for (int off = 1; off < 8; off <<= 1) {
        float om1 = __shfl_xor(m1, off), om2 = __shfl_xor(m2, off);
        float n1 = fmaxf(m1, om1);
        float n2 = fmaxf(fminf(m1, om1), fmaxf(m2, om2));
        m1 = n1; m2 = n2;
    }
    float gs = m1 + m2;
    float gsc[8];
#pragma unroll
    for (int i = 0; i < 8; ++i) gsc[i] = __shfl(gs, i*8);
    unsigned dropped = 0; float lastdrop = 0.f;
#pragma unroll
    for (int itd = 0; itd < 4; ++itd) {
        float mn = 1e38f; int mi = 0;
#pragma unroll
        for (int i = 0; i < 8; ++i)
            if (!((dropped >> i) & 1) && gsc[i] < mn) { mn = gsc[i]; mi = i; }
        dropped |= 1u << mi; lastdrop = mn;
    }
    float minkeep = 1e38f;
#pragma unroll
    for (int i = 0; i < 8; ++i)
        if (!((dropped >> i) & 1)) minkeep = fminf(minkeep, gsc[i]);
    float gmargin = minkeep - lastdrop;

    float cv[4];
#pragma unroll
    for (int j = 0; j < 4; ++j)
        cv[j] = ((dropped >> (ce[j] >> 5)) & 1) ? 0.0f : bv[j];

    float vals[9]; int ind[9];
#pragma unroll
    for (int r = 0; r < 9; ++r) {
        float lv = -1e38f; int li = 0x7fffffff;
#pragma unroll
        for (int j = 0; j < 4; ++j)
            if (cv[j] > lv || (cv[j] == lv && ce[j] < li)) { lv = cv[j]; li = ce[j]; }
#pragma unroll
        for (int off = 32; off >= 1; off >>= 1) {
            float ov = __shfl_xor(lv, off);
            int   oi = __shfl_xor(li, off);
            if (ov > lv || (ov == lv && oi < li)) { lv = ov; li = oi; }
        }
        vals[r] = lv; ind[r] = li;
#pragma unroll
        for (int j = 0; j < 4; ++j)
            if (ce[j] == li) cv[j] = -1e38f;
    }
    float mingap = 1e38f;
#pragma unroll
    for (int r = 0; r < 8; ++r) mingap = fminf(mingap, vals[r] - vals[r+1]);

    int myi = 0;
#pragma unroll
    for (int r = 0; r < 8; ++r) if (lane == r) myi = ind[r];
    float sv = (lane < 8) ? ss[myi] : 0.f;
    float sum = sv;
#pragma unroll
    for (int off = 1; off < 8; off <<= 1) sum += __shfl_xor(sum, off);
    if (lane < 8) {
        oIdx[tok*8 + lane] = (float)myi;
        oVal[tok*8 + lane] = sv / (sum + 1e-20f) * 2.5f;
    }
    if (flagCtr && lane == 0 && (mingap < TAU || gmargin < TAUG)) {
        unsigned p = atomicAdd(flagCtr, 1u);
        flagList[p] = (int)tok;
    }
}

/* ================= Kernel 3: reduce partials + sigmoid + gating (4 tok/block) === */
__global__ __launch_bounds__(256, 4)
void gate_topk(const float* __restrict__ partials, const float* __restrict__ bias,
               float* __restrict__ oIdx, float* __restrict__ oVal,
               unsigned* ctr, int* list)
{
    __shared__ float gb[4][256];
    __shared__ float ss[4][256];
    int wid = threadIdx.x >> 6, lane = threadIdx.x & 63;
    size_t tok = (size_t)blockIdx.x * 4 + wid;
    const float* p0 = partials + tok * NEXP;
    const float* p1 = partials + (size_t)NTOK * NEXP + tok * NEXP;
#pragma unroll
    for (int j = 0; j < 4; ++j) {
        int e = lane + 64*j;
        gb[wid][e] = p0[e] + p1[e];
    }
    wave_gate_topk(gb[wid], ss[wid], bias, lane, tok, oIdx, oVal, ctr, list);
}

/* ================= Kernel 4: fp32 recompute of margin-flagged tokens ============
   One token per block iteration; x row staged in LDS; each wave owns 64 experts,
   64 lanes split K (coalesced 16B W loads); shuffle-reduce; wave 0 re-gates.   */
__global__ __launch_bounds__(256, 4)
void gate_refine(const float* __restrict__ x, const float* __restrict__ w,
                 const float* __restrict__ bias,
                 float* __restrict__ oIdx, float* __restrict__ oVal,
                 const unsigned* __restrict__ ctr, const int* __restrict__ list)
{
    __shared__ float xsh[HDIM];      /* 16 KiB */
    __shared__ float gb[NEXP];
    __shared__ float ss[NEXP];
    const int nf = (int)*ctr;
    const int wid = threadIdx.x >> 6, lane = threadIdx.x & 63;

    for (int fi = blockIdx.x; fi < nf; fi += gridDim.x) {
        int tok = list[fi];
        __syncthreads();             /* protect xsh/gb from prev iteration */
        const float4* xsrc = (const float4*)(x + (size_t)tok * HDIM);
        float4* xd = (float4*)xsh;
        for (int j = threadIdx.x; j < HDIM/4; j += 256) xd[j] = xsrc[j];
        __syncthreads();

        for (int e8 = 0; e8 < 64; e8 += 2) {
            int e0 = wid*64 + e8;
            const float4* w0 = (const float4*)(w + (size_t)e0 * HDIM);
            const float4* w1 = (const float4*)(w + (size_t)(e0+1) * HDIM);
            float a0 = 0.f, a1 = 0.f;
            for (int k = lane; k < HDIM/4; k += 64) {
                float4 xv = xd[k];
                float4 wa = w0[k];
                float4 wb = w1[k];
                a0 += wa.x*xv.x + wa.y*xv.y + wa.z*xv.z + wa.w*xv.w;
                a1 += wb.x*xv.x + wb.y*xv.y + wb.z*xv.z + wb.w*xv.w;
            }
#pragma unroll
            for (int off = 32; off >= 1; off >>= 1) {
                a0 += __shfl_xor(a0, off);
                a1 += __shfl_xor(a1, off);
            }
            if (lane == 0) { gb[e0] = a0; gb[e0+1] = a1; }
        }
        __syncthreads();
        if (wid == 0)
            wave_gate_topk(gb, ss, bias, lane, (size_t)tok,
                           oIdx, oVal, nullptr, nullptr);
    }
}

extern "C" void kernel_launch(void* const* d_in, const int* in_sizes, int n_in,
                              void* d_out, int out_size, void* d_ws, size_t ws_size,
                              hipStream_t stream) {
    const float* x    = (const float*)d_in[0];
    const float* w    = (const float*)d_in[1];
    const float* bias = (const float*)d_in[2];
    const int ntok = in_sizes[0] / HDIM;          /* 16384 */

    char* ws = (char*)d_ws;
    float* partials      = (float*)ws;
    unsigned short* wws  = (unsigned short*)(ws + WS_WSPLIT);
    unsigned* ctr        = (unsigned*)(ws + WS_CTR);
    int* list            = (int*)(ws + WS_LIST);
    float* oIdx = (float*)d_out;
    float* oVal = (float*)d_out + (size_t)ntok * TOPK;

    hipMemsetAsync(ctr, 0, 4, stream);
    convert_w  <<<512, 256, 0, stream>>>(w, wws);
    gate_gemm  <<<(ntok/BM) * KSPLIT, 512, 0, stream>>>(x, wws, partials);
    gate_topk  <<<ntok/4, 256, 0, stream>>>(partials, bias, oIdx, oVal, ctr, list);
    gate_refine<<<1024, 256, 0, stream>>>(x, w, bias, oIdx, oVal, ctr, list);
}